// Round 1
// baseline (281.582 us; speedup 1.0000x reference)
//
#include <hip/hip_runtime.h>
#include <hip/hip_bf16.h>
#include <stdint.h>

#define EMBED 1024
#define HEADS 16
#define CTX   2048
#define BATCH 4
#define HD    64
#define M_TOT (BATCH*CTX)   // 8192
#define NKT   (EMBED/64)    // 16 K-tiles of 64

typedef unsigned short u16;
typedef __attribute__((ext_vector_type(8))) short short8;   // 8 bf16 (4 VGPRs)
typedef __attribute__((ext_vector_type(4))) float floatx4;  // MFMA C/D

typedef const __attribute__((address_space(1))) unsigned int g_u32;
typedef __attribute__((address_space(3))) unsigned int l_u32;

__device__ __forceinline__ void async16(const void* g, void* l) {
    __builtin_amdgcn_global_load_lds((g_u32*)g, (l_u32*)l, 16, 0, 0);
}

__device__ __forceinline__ u16 f2bf(float f) {          // round-nearest-even
    uint32_t u = __float_as_uint(f);
    uint32_t r = (u + 0x7FFFu + ((u >> 16) & 1u)) >> 16;
    return (u16)r;
}

// ---------------- fp32 -> bf16 converts ----------------
__global__ void cvt_kernel(const float* __restrict__ src, u16* __restrict__ dst, int n) {
    int i = (blockIdx.x * blockDim.x + threadIdx.x) * 4;
    if (i >= n) return;
    float4 f = *(const float4*)(src + i);
    ushort4 o;
    o.x = f2bf(f.x); o.y = f2bf(f.y); o.z = f2bf(f.z); o.w = f2bf(f.w);
    *(ushort4*)(dst + i) = o;
}

__global__ void cvt_w_kernel(const float* __restrict__ s0, const float* __restrict__ s1,
                             const float* __restrict__ s2, const float* __restrict__ s3,
                             u16* __restrict__ d0, u16* __restrict__ d1,
                             u16* __restrict__ d2, u16* __restrict__ d3) {
    const int wsel = blockIdx.y;
    const float* src = (wsel == 0) ? s0 : (wsel == 1) ? s1 : (wsel == 2) ? s2 : s3;
    u16*       dst  = (wsel == 0) ? d0 : (wsel == 1) ? d1 : (wsel == 2) ? d2 : d3;
    int i = (blockIdx.x * blockDim.x + threadIdx.x) * 4;
    float4 f = *(const float4*)(src + i);
    ushort4 o;
    o.x = f2bf(f.x); o.y = f2bf(f.y); o.z = f2bf(f.z); o.w = f2bf(f.w);
    *(ushort4*)(dst + i) = o;
}

// ================= fused QKV GEMM, 256x256 tile, pipelined 4-phase/K-tile =================
// 512 threads = 8 waves (2M x 4N). LDS: 2 dbuf x (A 32KB + B 32KB) = 128 KB.
// Per K-tile: 4 phases, each {ds_read subtile | issue 1 half-tile prefetch |
// s_barrier | lgkmcnt(0) | setprio(1) 16xMFMA setprio(0) | s_barrier}.
// Counted vmcnt(4) once per K-tile at phase 4 (2 half-tiles in flight across
// the boundary); vmcnt(0) only in the 2-iteration tail. Quadrant order
// (mh0,nh0)->(mh1,nh0)->(mh1,nh1)->(mh0,nh1) gives 12/8/4/0 ds_reads per phase.
// Stage slots: ph1=B-lo(kt+1)->buf^1, ph2=B-hi(kt+1)->buf^1 (old B last read
// its ph3), ph3=A-lo(kt+2)->buf, ph4=A-hi(kt+2)->buf (cur A last read ph2);
// every overwrite target's last reader passed a phase-end barrier first.
__global__ __launch_bounds__(512, 2)
void gemm_qkv(const u16* __restrict__ A,
              const u16* __restrict__ Wq, const u16* __restrict__ Wk, const u16* __restrict__ Wv,
              const float* __restrict__ bq, const float* __restrict__ bk, const float* __restrict__ bv,
              u16* __restrict__ oq, u16* __restrict__ ok, u16* __restrict__ ov,
              float qscale)
{
    __shared__ u16 As[2][256*64];   // 2 x 32 KB
    __shared__ u16 Bs[2][256*64];   // 2 x 32 KB

    const int tid  = threadIdx.x;
    const int lane = tid & 63;
    const int wid  = tid >> 6;          // 0..7
    const int wm = wid >> 2, wn = wid & 3;
    const int quad = lane >> 4;
    const int l16  = lane & 15;
    const int bm0 = blockIdx.x * 256;
    const int sel = blockIdx.y >> 2;          // 0=Q 1=K 2=V
    const int bn0 = (blockIdx.y & 3) * 256;

    const u16*  Bw   = (sel == 0) ? Wq : (sel == 1) ? Wk : Wv;
    const float* bias = (sel == 0) ? bq : (sel == 1) ? bk : bv;
    u16*        out  = (sel == 0) ? oq : (sel == 1) ? ok : ov;
    const float scale = (sel == 0) ? qscale : 1.0f;

    // staging geometry: thread t covers rows {r0, r0+64} of a 128-row half,
    // 16B chunk (t&7), source k pre-swizzled by the same XOR the reads use.
    const int r0   = tid >> 3;                       // 0..63
    const int joff = ((tid & 7) ^ (r0 & 7)) * 8;     // shorts
    const u16* Ag = A  + (size_t)(bm0 + r0) * EMBED + joff;
    const u16* Bg = Bw + (size_t)(bn0 + r0) * EMBED + joff;
    char* AsBase = (char*)As;   // buf b at + b*32768
    char* BsBase = (char*)Bs;
    const int dstb = r0*128 + (tid & 7)*16;          // linear byte in half

    auto stageA = [&](int buf, int kt, int mh) {
        const u16* g = Ag + (size_t)(mh*128) * EMBED + kt*64;
        char* d = AsBase + buf*32768 + mh*16384 + dstb;
        async16(g,                    d);
        async16(g + (size_t)64*EMBED, d + 8192);
    };
    auto stageB = [&](int buf, int kt, int nh) {
        const u16* g = Bg + (size_t)(nh*128) * EMBED + kt*64;
        char* d = BsBase + buf*32768 + nh*16384 + dstb;
        async16(g,                    d);
        async16(g + (size_t)64*EMBED, d + 8192);
    };

    const int sw = l16 & 7;   // row&7 for every fragment row we touch

    // ---- prologue: kt0 fully + kt1 A halves (steady-state stream order)
    stageA(0, 0, 0); stageA(0, 0, 1);
    stageB(0, 0, 0); stageB(0, 0, 1);
    stageA(1, 1, 0); stageA(1, 1, 1);
    asm volatile("s_waitcnt vmcnt(4)" ::: "memory");   // kt0's 4 halves done
    __builtin_amdgcn_s_barrier();

    floatx4 acc[8][4] = {};   // [mh*4+mi][nh*2+ni]

#pragma unroll 1
    for (int kt = 0; kt < NKT; ++kt) {
        const int p = kt & 1;
        const char* Ab = AsBase + p*32768;
        const char* Bb = BsBase + p*32768;

        short8 alo[4][2], ahi[4][2], b0[2][2], b1[2][2];

        // ---------- phase 1: (mh0, nh0) — 12 ds_reads ----------
#pragma unroll
        for (int mi = 0; mi < 4; ++mi)
#pragma unroll
            for (int ks = 0; ks < 2; ++ks)
                alo[mi][ks] = *(const short8*)(Ab + (wm*128 + mi*16 + l16)*128
                                               + (((ks*4 + quad) ^ sw) * 16));
#pragma unroll
        for (int ni = 0; ni < 2; ++ni)
#pragma unroll
            for (int ks = 0; ks < 2; ++ks)
                b0[ni][ks] = *(const short8*)(Bb + (wn*64 + ni*16 + l16)*128
                                              + (((ks*4 + quad) ^ sw) * 16));
        if (kt + 1 < NKT) stageB(p ^ 1, kt + 1, 0);
        __builtin_amdgcn_s_barrier();
        asm volatile("s_waitcnt lgkmcnt(0)" ::: "memory");
        __builtin_amdgcn_s_setprio(1);
#pragma unroll
        for (int mi = 0; mi < 4; ++mi)
#pragma unroll
            for (int ni = 0; ni < 2; ++ni)
#pragma unroll
                for (int ks = 0; ks < 2; ++ks)
                    acc[mi][ni] = __builtin_amdgcn_mfma_f32_16x16x32_bf16(
                        alo[mi][ks], b0[ni][ks], acc[mi][ni], 0, 0, 0);
        __builtin_amdgcn_s_setprio(0);
        __builtin_amdgcn_s_barrier();

        // ---------- phase 2: (mh1, nh0) — 8 ds_reads ----------
#pragma unroll
        for (int mi = 0; mi < 4; ++mi)
#pragma unroll
            for (int ks = 0; ks < 2; ++ks)
                ahi[mi][ks] = *(const short8*)(Ab + (wm*128 + 64 + mi*16 + l16)*128
                                               + (((ks*4 + quad) ^ sw) * 16));
        if (kt + 1 < NKT) stageB(p ^ 1, kt + 1, 1);
        __builtin_amdgcn_s_barrier();
        asm volatile("s_waitcnt lgkmcnt(0)" ::: "memory");
        __builtin_amdgcn_s_setprio(1);
#pragma unroll
        for (int mi = 0; mi < 4; ++mi)
#pragma unroll
            for (int ni = 0; ni < 2; ++ni)
#pragma unroll
                for (int ks = 0; ks < 2; ++ks)
                    acc[4 + mi][ni] = __builtin_amdgcn_mfma_f32_16x16x32_bf16(
                        ahi[mi][ks], b0[ni][ks], acc[4 + mi][ni], 0, 0, 0);
        __builtin_amdgcn_s_setprio(0);
        __builtin_amdgcn_s_barrier();

        // ---------- phase 3: (mh1, nh1) — 4 ds_reads ----------
#pragma unroll
        for (int ni = 0; ni < 2; ++ni)
#pragma unroll
            for (int ks = 0; ks < 2; ++ks)
                b1[ni][ks] = *(const short8*)(Bb + (wn*64 + 32 + ni*16 + l16)*128
                                              + (((ks*4 + quad) ^ sw) * 16));
        if (kt + 2 < NKT) stageA(p, kt + 2, 0);
        __builtin_amdgcn_s_barrier();
        asm volatile("s_waitcnt lgkmcnt(0)" ::: "memory");
        __builtin_amdgcn_s_setprio(1);
#pragma unroll
        for (int mi = 0; mi < 4; ++mi)
#pragma unroll
            for (int ni = 0; ni < 2; ++ni)
#pragma unroll
                for (int ks = 0; ks < 2; ++ks)
                    acc[4 + mi][2 + ni] = __builtin_amdgcn_mfma_f32_16x16x32_bf16(
                        ahi[mi][ks], b1[ni][ks], acc[4 + mi][2 + ni], 0, 0, 0);
        __builtin_amdgcn_s_setprio(0);
        __builtin_amdgcn_s_barrier();

        // ---------- phase 4: (mh0, nh1) — 0 ds_reads, counted vmcnt ----------
        if (kt + 2 < NKT) {
            stageA(p, kt + 2, 1);
            asm volatile("s_waitcnt vmcnt(4)" ::: "memory");   // kt+1 fully staged
        } else {
            asm volatile("s_waitcnt vmcnt(0)" ::: "memory");   // tail drain
        }
        __builtin_amdgcn_s_barrier();
        __builtin_amdgcn_s_setprio(1);
#pragma unroll
        for (int mi = 0; mi < 4; ++mi)
#pragma unroll
            for (int ni = 0; ni < 2; ++ni)
#pragma unroll
                for (int ks = 0; ks < 2; ++ks)
                    acc[mi][2 + ni] = __builtin_amdgcn_mfma_f32_16x16x32_bf16(
                        alo[mi][ks], b1[ni][ks], acc[mi][2 + ni], 0, 0, 0);
        __builtin_amdgcn_s_setprio(0);
        __builtin_amdgcn_s_barrier();
    }

    // ---------- epilogue (same math/layout as verified 128^2 kernel) ----------
#pragma unroll
    for (int mh = 0; mh < 2; ++mh)
#pragma unroll
     for (int mi = 0; mi < 4; ++mi)
#pragma unroll
      for (int nh = 0; nh < 2; ++nh)
#pragma unroll
       for (int ni = 0; ni < 2; ++ni) {
            const int col = bn0 + wn*64 + nh*32 + ni*16 + l16;
            const float bvv = bias[col];
#pragma unroll
            for (int r = 0; r < 4; ++r) {
                const int row = bm0 + wm*128 + mh*64 + mi*16 + quad*4 + r;
                const float v = (acc[mh*4 + mi][nh*2 + ni][r] + bvv) * scale;
                const int bb = row >> 11, t = row & 2047;
                const int hh = col >> 6,  d = col & 63;
                if (sel != 2)
                    out[((size_t)(bb*HEADS + hh)*CTX + t)*HD + d] = f2bf(v);
                else
                    out[((size_t)(bb*HEADS + hh)*HD + d)*CTX + t] = f2bf(v);
            }
       }
}

// ================= projection GEMM (fp32 out), BK=64 =================
__global__ __launch_bounds__(256)
void gemm_proj(const u16* __restrict__ A, const u16* __restrict__ Bw,
               const float* __restrict__ bias, float* __restrict__ out)
{
    __shared__ u16 As[128*64];
    __shared__ u16 Bs[128*64];
    const int tid  = threadIdx.x;
    const int lane = tid & 63;
    const int wid  = tid >> 6;
    const int wm = wid >> 1, wn = wid & 1;
    const int quad = lane >> 4;
    const int l16  = lane & 15;
    const int bm0 = blockIdx.x * 128;
    const int bn0 = blockIdx.y * 128;

    floatx4 acc[4][4] = {};

    const int r0   = tid >> 3;
    const int joff = ((tid & 7) ^ ((tid >> 3) & 7)) * 8;
    const u16* Ag0 = A  + (size_t)(bm0 + r0      ) * EMBED + joff;
    const u16* Ag1 = A  + (size_t)(bm0 + r0 + 32 ) * EMBED + joff;
    const u16* Ag2 = A  + (size_t)(bm0 + r0 + 64 ) * EMBED + joff;
    const u16* Ag3 = A  + (size_t)(bm0 + r0 + 96 ) * EMBED + joff;
    const u16* Bg0 = Bw + (size_t)(bn0 + r0      ) * EMBED + joff;
    const u16* Bg1 = Bw + (size_t)(bn0 + r0 + 32 ) * EMBED + joff;
    const u16* Bg2 = Bw + (size_t)(bn0 + r0 + 64 ) * EMBED + joff;
    const u16* Bg3 = Bw + (size_t)(bn0 + r0 + 96 ) * EMBED + joff;
    char* AsB = (char*)As;
    char* BsB = (char*)Bs;
    const int wbyte = wid * 1024;
    const int fpos0 = (quad ^ (l16 & 7)) * 8;
    const int fpos1 = fpos0 ^ 32;

    for (int kk = 0; kk < EMBED; kk += 64) {
        __syncthreads();
        async16(Ag0 + kk, AsB + wbyte);
        async16(Ag1 + kk, AsB + wbyte + 4096);
        async16(Ag2 + kk, AsB + wbyte + 8192);
        async16(Ag3 + kk, AsB + wbyte + 12288);
        async16(Bg0 + kk, BsB + wbyte);
        async16(Bg1 + kk, BsB + wbyte + 4096);
        async16(Bg2 + kk, BsB + wbyte + 8192);
        async16(Bg3 + kk, BsB + wbyte + 12288);
        __syncthreads();

#pragma unroll
        for (int ks = 0; ks < 2; ks++) {
            const int fp = ks ? fpos1 : fpos0;
            short8 a[4], b[4];
#pragma unroll
            for (int i = 0; i < 4; i++)
                a[i] = *(const short8*)(As + (wm*64 + i*16 + l16)*64 + fp);
#pragma unroll
            for (int i = 0; i < 4; i++)
                b[i] = *(const short8*)(Bs + (wn*64 + i*16 + l16)*64 + fp);
#pragma unroll
            for (int i = 0; i < 4; i++)
#pragma unroll
                for (int j = 0; j < 4; j++)
                    acc[i][j] = __builtin_amdgcn_mfma_f32_16x16x32_bf16(a[i], b[j], acc[i][j], 0, 0, 0);
        }
    }

#pragma unroll
    for (int i = 0; i < 4; i++) {
#pragma unroll
        for (int j = 0; j < 4; j++) {
            const int col = bn0 + wn*64 + j*16 + l16;
            const float bvv = bias[col];
#pragma unroll
            for (int r = 0; r < 4; r++) {
                const int row = bm0 + wm*64 + i*16 + quad*4 + r;
                out[(size_t)row * EMBED + col] = acc[i][j][r] + bvv;
            }
        }
    }
}

// ---------------- flash attention v3: 128 q/block, S^T order, swizzled P ----------------
__global__ __launch_bounds__(256)
void attn_kernel(const u16* __restrict__ Q, const u16* __restrict__ K,
                 const u16* __restrict__ Vt, u16* __restrict__ O)
{
    __shared__ u16 Ks[2][64*64];     // 2 x 8 KB
    __shared__ u16 Vs[2][64*64];     // 2 x 8 KB   Vs[d][ki]
    __shared__ u16 Ps[4*32*64];      // 16 KB, per-wave 32 rows x 64 ki

    const int tid  = threadIdx.x, lane = tid & 63, w = tid >> 6;
    const int quad = lane >> 4, l16 = lane & 15;

    const int lid  = blockIdx.x;            // 0..511
    const int xcd  = lid & 7;
    const int slot = lid >> 3;              // 0..63
    const int bh   = xcd * 8 + (slot >> 3);
    const int bx   = slot & 7;              // 0..7
    const int h    = bh & (HEADS - 1);
    const int b    = bh >> 4;

    const u16* Qh = Q  + (size_t)bh * CTX * HD;
    const u16* Kh = K  + (size_t)bh * CTX * HD;
    const u16* Vh = Vt + (size_t)bh * HD * CTX;

    const int srow = tid >> 3;
    const int joff = ((tid & 7) ^ (srow & 7)) * 8;
    const int wbyte = w * 1024;
    char* PwB = (char*)(Ps + w * 32 * 64);
    const int sw = l16 & 7;                 // swizzle key (row&7 for all our rows)

    auto stage = [&](int kt, int buf) {
        char* kb = (char*)(&Ks[buf][0]) + wbyte;
        char* vb = (char*)(&Vs[buf][0]) + wbyte;
        async16(Kh + (size_t)(kt*64 + srow     )*HD + joff, kb);
        async16(Kh + (size_t)(kt*64 + srow + 32)*HD + joff, kb + 4096);
        async16(Vh + (size_t)(srow     )*CTX + kt*64 + joff, vb);
        async16(Vh + (size_t)(srow + 32)*CTX + kt*64 + joff, vb + 4096);
    };

    int par = 0;
    stage(0, 0);

#pragma unroll 1
    for (int pass = 0; pass < 2; pass++) {
        const int qb  = (pass == 0) ? bx : (15 - bx);
        const int qb0 = qb * 128;
        const int KT  = 2*qb + 2;

        // Q fragments (B-operand: n=q=l16, k=d): qf[subtile][kstep]
        short8 qf[2][2];
#pragma unroll
        for (int st = 0; st < 2; st++)
#pragma unroll
            for (int ks = 0; ks < 2; ks++)
                qf[st][ks] = *(const short8*)(Qh + (size_t)(qb0 + w*32 + st*16 + l16)*HD
                                              + ks*32 + quad*8);

        float lsum[2] = {0.f, 0.f};
        floatx4 o_acc[2][4] = {};

        for (int kt = 0; kt < KT; kt++) {
            __syncthreads();   // drains stage(kt), in flight since previous compute

            if (kt + 1 < KT)      stage(kt + 1, par ^ 1);
            else if (pass == 0)   stage(0,      par ^ 1);

            const char* KcB = (const char*)(&Ks[par][0]);
            const char* VcB = (const char*)(&Vs[par][0]);

            // S^T = K Q^T : m=ki (row=quad*4+r), n=q (col=l16)
            floatx4 s[2][4] = {};
#pragma unroll
            for (int ks = 0; ks < 2; ks++) {
#pragma unroll
                for (int ni = 0; ni < 4; ni++) {
                    short8 kf = *(const short8*)(KcB + (ni*16 + l16)*128
                                                 + (((4*ks + quad) ^ sw) * 16));
                    s[0][ni] = __builtin_amdgcn_mfma_f32_16x16x32_bf16(kf, qf[0][ks], s[0][ni], 0, 0, 0);
                    s[1][ni] = __builtin_amdgcn_mfma_f32_16x16x32_bf16(kf, qf[1][ks], s[1][ni], 0, 0, 0);
                }
            }

            // P = exp2(S'), mask on last two tiles, packed b64 stores to swizzled P
            const bool mt = (kt >= 2*qb);
            const int key0 = kt * 64;
#pragma unroll
            for (int st = 0; st < 2; st++) {
                const int qrow = qb0 + w*32 + st*16 + l16;
#pragma unroll
                for (int ni = 0; ni < 4; ni++) {
                    float p[4];
#pragma unroll
                    for (int r = 0; r < 4; r++) {
                        float v = s[st][ni][r];
                        if (mt) {
                            const int key = key0 + ni*16 + quad*4 + r;
                            if (key > qrow) v = -INFINITY;
                        }
                        p[r] = __builtin_amdgcn_exp2f(v);
                        lsum[st] += p[r];
                    }
                    uint2 pk;
                    pk.x = (__float_as_uint(p[0]) >> 16) | (__float_as_uint(p[1]) & 0xFFFF0000u);
                    pk.y = (__float_as_uint(p[2]) >> 16) | (__float_as_uint(p[3]) & 0xFFFF0000u);
                    *(uint2*)(PwB + (st*16 + l16)*128
                              + (((2*ni + (quad >> 1)) ^ sw) * 16) + (quad & 1) * 8) = pk;
                }
            }

            // O += P V : A=P (m=q), B=Vt rows (n=d, k=ki)
#pragma unroll
            for (int ks = 0; ks < 2; ks++) {
                const int pco = ((4*ks + quad) ^ sw) * 16;
                short8 pf0 = *(const short8*)(PwB + (l16     )*128 + pco);
                short8 pf1 = *(const short8*)(PwB + (16 + l16)*128 + pco);
#pragma unroll
                for (int ni = 0; ni < 4; ni++) {
                    short8 vf = *(const short8*)(VcB + (ni*16 + l16)*128 + pco);
                    o_acc[0][ni] = __builtin_amdgcn_mfma_f32_16x16x32_bf16(pf0, vf, o_acc[0][ni], 0, 0, 0);
                    o_acc[1][ni] = __builtin_amdgcn_mfma_f32_16x16x32_bf16(pf1, vf, o_acc[1][ni], 0, 0, 0);
                }
            }

            par ^= 1;
        }

        // l-sum: reduce across the 4 quads (lane l has sum for q=l&15), then
        // redistribute reciprocal to the C-layout lanes (q = quad*4+r).
        float linv[2][4];
#pragma unroll
        for (int st = 0; st < 2; st++) {
            lsum[st] += __shfl_xor(lsum[st], 16);
            lsum[st] += __shfl_xor(lsum[st], 32);
            const float rinv = 1.f / lsum[st];
#pragma unroll
            for (int r = 0; r < 4; r++)
                linv[st][r] = __shfl(rinv, quad*4 + r);
        }

        u16* Ob = O + ((size_t)b * CTX) * EMBED + (size_t)h * HD;
#pragma unroll
        for (int st = 0; st < 2; st++)
#pragma unroll
            for (int ni = 0; ni < 4; ni++)
#pragma unroll
                for (int r = 0; r < 4; r++) {
                    const int qrow = qb0 + w*32 + st*16 + quad*4 + r;
                    Ob[(size_t)qrow * EMBED + ni*16 + l16] = f2bf(o_acc[st][ni][r] * linv[st][r]);
                }
    }
}

// ---------------- launcher ----------------
extern "C" void kernel_launch(void* const* d_in, const int* in_sizes, int n_in,
                              void* d_out, int out_size, void* d_ws, size_t ws_size,
                              hipStream_t stream) {
    const float* x  = (const float*)d_in[0];
    const float* Wq = (const float*)d_in[1];
    const float* bq = (const float*)d_in[2];
    const float* Wk = (const float*)d_in[3];
    const float* bk = (const float*)d_in[4];
    const float* Wv = (const float*)d_in[5];
    const float* bv = (const float*)d_in[6];
    const float* Wp = (const float*)d_in[7];
    const float* bp = (const float*)d_in[8];

    char* ws = (char*)d_ws;
    const size_t XSZ = (size_t)M_TOT * EMBED * 2;   // 16 MB
    const size_t WSZ = (size_t)EMBED * EMBED * 2;   // 2 MB
    u16* xb  = (u16*)ws;                 ws += XSZ;
    u16* wqb = (u16*)ws;                 ws += WSZ;
    u16* wkb = (u16*)ws;                 ws += WSZ;
    u16* wvb = (u16*)ws;                 ws += WSZ;
    u16* wpb = (u16*)ws;                 ws += WSZ;
    u16* qg  = (u16*)ws;                 ws += XSZ;
    u16* kg  = (u16*)ws;                 ws += XSZ;
    u16* vtg = (u16*)ws;                 ws += XSZ;
    u16* og  = xb;   // x-bf16 dead after QKV GEMM; attn output reuses it

    const int nX = M_TOT * EMBED;
    const int nW = EMBED * EMBED;
    cvt_kernel<<<nX/1024, 256, 0, stream>>>(x, xb, nX);
    cvt_w_kernel<<<dim3(nW/1024, 4), 256, 0, stream>>>(Wq, Wk, Wv, Wp, wqb, wkb, wvb, wpb);

    const float qscale = 0.125f * 1.44269504f;  // 1/sqrt(64) * log2(e)
    gemm_qkv<<<dim3(M_TOT/256, 12), 512, 0, stream>>>(xb, wqb, wkb, wvb, bq, bk, bv,
                                                      qg, kg, vtg, qscale);

    attn_kernel<<<dim3(512), 256, 0, stream>>>(qg, kg, vtg, og);

    gemm_proj<<<dim3(M_TOT/128, EMBED/128), 256, 0, stream>>>(og, wpb, bp, (float*)d_out);
}

// Round 2
// 279.924 us; speedup vs baseline: 1.0059x; 1.0059x over previous
//
#include <hip/hip_runtime.h>
#include <hip/hip_bf16.h>
#include <stdint.h>

#define EMBED 1024
#define HEADS 16
#define CTX   2048
#define BATCH 4
#define HD    64
#define M_TOT (BATCH*CTX)   // 8192
#define NKT   (EMBED/64)    // 16 K-tiles of 64

typedef unsigned short u16;
typedef __attribute__((ext_vector_type(8))) short short8;   // 8 bf16 (4 VGPRs)
typedef __attribute__((ext_vector_type(4))) float floatx4;  // MFMA C/D

typedef const __attribute__((address_space(1))) unsigned int g_u32;
typedef __attribute__((address_space(3))) unsigned int l_u32;

__device__ __forceinline__ void async16(const void* g, void* l) {
    __builtin_amdgcn_global_load_lds((g_u32*)g, (l_u32*)l, 16, 0, 0);
}

__device__ __forceinline__ u16 f2bf(float f) {          // round-nearest-even
    uint32_t u = __float_as_uint(f);
    uint32_t r = (u + 0x7FFFu + ((u >> 16) & 1u)) >> 16;
    return (u16)r;
}

// ---------------- fp32 -> bf16 converts ----------------
__global__ void cvt_kernel(const float* __restrict__ src, u16* __restrict__ dst, int n) {
    int i = (blockIdx.x * blockDim.x + threadIdx.x) * 4;
    if (i >= n) return;
    float4 f = *(const float4*)(src + i);
    ushort4 o;
    o.x = f2bf(f.x); o.y = f2bf(f.y); o.z = f2bf(f.z); o.w = f2bf(f.w);
    *(ushort4*)(dst + i) = o;
}

__global__ void cvt_w_kernel(const float* __restrict__ s0, const float* __restrict__ s1,
                             const float* __restrict__ s2, const float* __restrict__ s3,
                             u16* __restrict__ d0, u16* __restrict__ d1,
                             u16* __restrict__ d2, u16* __restrict__ d3) {
    const int wsel = blockIdx.y;
    const float* src = (wsel == 0) ? s0 : (wsel == 1) ? s1 : (wsel == 2) ? s2 : s3;
    u16*       dst  = (wsel == 0) ? d0 : (wsel == 1) ? d1 : (wsel == 2) ? d2 : d3;
    int i = (blockIdx.x * blockDim.x + threadIdx.x) * 4;
    float4 f = *(const float4*)(src + i);
    ushort4 o;
    o.x = f2bf(f.x); o.y = f2bf(f.y); o.z = f2bf(f.z); o.w = f2bf(f.w);
    *(ushort4*)(dst + i) = o;
}

// ================= fused QKV GEMM, 256x256 tile, m201-style 8-phase/2-K-tiles =================
// 512 threads = 8 waves (2M x 4N). LDS: 2 dbuf x (A 32KB + B 32KB) = 128 KB.
// Region last-reads within a 4-phase K-tile: A-half ph2, B-half ph3 (wave wm=0
// reads A-lo in BOTH ph1+ph2; wn<2 waves read B-lo in ph1+ph3). Stage slots
// honor that: ph3=A-lo(kt0+2), ph4=A-hi+B-lo(kt0+2)+vmcnt(6), ph5=B-hi(kt0+2),
// ph7=A-lo(kt1+2), ph8=A-hi+B-lo+B-hi(kt1+2)+vmcnt(8). Tightest issue->wait
// distance = 3-4 phases (>= HBM latency at MFMA-rate phases); 3-4 half-tiles
// in flight across every wait; vmcnt->0 only in the last iteration.
__global__ __launch_bounds__(512, 2)
void gemm_qkv(const u16* __restrict__ A,
              const u16* __restrict__ Wq, const u16* __restrict__ Wk, const u16* __restrict__ Wv,
              const float* __restrict__ bq, const float* __restrict__ bk, const float* __restrict__ bv,
              u16* __restrict__ oq, u16* __restrict__ ok, u16* __restrict__ ov,
              float qscale)
{
    __shared__ u16 As[2][256*64];   // 2 x 32 KB
    __shared__ u16 Bs[2][256*64];   // 2 x 32 KB

    const int tid  = threadIdx.x;
    const int lane = tid & 63;
    const int wid  = tid >> 6;          // 0..7
    const int wm = wid >> 2, wn = wid & 3;
    const int quad = lane >> 4;
    const int l16  = lane & 15;
    const int bm0 = blockIdx.x * 256;
    const int sel = blockIdx.y >> 2;          // 0=Q 1=K 2=V
    const int bn0 = (blockIdx.y & 3) * 256;

    const u16*  Bw   = (sel == 0) ? Wq : (sel == 1) ? Wk : Wv;
    const float* bias = (sel == 0) ? bq : (sel == 1) ? bk : bv;
    u16*        out  = (sel == 0) ? oq : (sel == 1) ? ok : ov;
    const float scale = (sel == 0) ? qscale : 1.0f;

    // staging geometry: thread t covers rows {r0, r0+64} of a 128-row half,
    // 16B chunk (t&7), source k pre-swizzled by the same XOR the reads use.
    const int r0   = tid >> 3;                       // 0..63
    const int joff = ((tid & 7) ^ (r0 & 7)) * 8;     // shorts
    const u16* Ag = A  + (size_t)(bm0 + r0) * EMBED + joff;
    const u16* Bg = Bw + (size_t)(bn0 + r0) * EMBED + joff;
    const int dstb = r0*128 + (tid & 7)*16;          // linear byte in half

    auto stA = [&](int buf, int kt, int half) {
        const u16* g = Ag + (size_t)(half*128) * EMBED + kt*64;
        char* d = (char*)As + buf*32768 + half*16384 + dstb;
        async16(g,                    d);
        async16(g + (size_t)64*EMBED, d + 8192);
    };
    auto stB = [&](int buf, int kt, int half) {
        const u16* g = Bg + (size_t)(half*128) * EMBED + kt*64;
        char* d = (char*)Bs + buf*32768 + half*16384 + dstb;
        async16(g,                    d);
        async16(g + (size_t)64*EMBED, d + 8192);
    };

    const int sw = l16 & 7;   // row&7 for every fragment row we touch
    const char* A0 = (const char*)As;
    const char* B0 = (const char*)Bs;
    const char* A1 = (const char*)As + 32768;
    const char* B1 = (const char*)Bs + 32768;

    // ---- prologue: kt0=0 -> buf0, kt1=1 -> buf1 (16 loads)
    stA(0, 0, 0); stA(0, 0, 1); stB(0, 0, 0); stB(0, 0, 1);
    stA(1, 1, 0); stA(1, 1, 1); stB(1, 1, 0); stB(1, 1, 1);
    asm volatile("s_waitcnt vmcnt(8)" ::: "memory");   // kt0's 8 loads done
    __builtin_amdgcn_s_barrier();

    floatx4 acc[8][4] = {};   // [mh*4+mi][nh*2+ni]
    short8 al[4][2], ah[4][2], b0f[2][2], b1f[2][2];

#pragma unroll 1
    for (int it = 0; it < NKT/2; ++it) {
        const int kt0 = 2*it, kt1 = 2*it + 1;

        // ========== K-tile kt0 (buf0) ==========
        // ---- ph1: reads A-lo frag + B nh0 frag; MFMA (mh0,nh0)
#pragma unroll
        for (int mi = 0; mi < 4; ++mi)
#pragma unroll
            for (int ks = 0; ks < 2; ++ks)
                al[mi][ks] = *(const short8*)(A0 + (wm*128 + mi*16 + l16)*128
                                              + (((ks*4 + quad) ^ sw) * 16));
#pragma unroll
        for (int ni = 0; ni < 2; ++ni)
#pragma unroll
            for (int ks = 0; ks < 2; ++ks)
                b0f[ni][ks] = *(const short8*)(B0 + (wn*64 + ni*16 + l16)*128
                                               + (((ks*4 + quad) ^ sw) * 16));
        __builtin_amdgcn_s_barrier();
        asm volatile("s_waitcnt lgkmcnt(0)" ::: "memory");
        __builtin_amdgcn_s_setprio(1);
#pragma unroll
        for (int mi = 0; mi < 4; ++mi)
#pragma unroll
            for (int ni = 0; ni < 2; ++ni)
#pragma unroll
                for (int ks = 0; ks < 2; ++ks)
                    acc[mi][ni] = __builtin_amdgcn_mfma_f32_16x16x32_bf16(
                        al[mi][ks], b0f[ni][ks], acc[mi][ni], 0, 0, 0);
        __builtin_amdgcn_s_setprio(0);
        __builtin_amdgcn_s_barrier();

        // ---- ph2: reads A-hi frag; MFMA (mh1,nh0)
#pragma unroll
        for (int mi = 0; mi < 4; ++mi)
#pragma unroll
            for (int ks = 0; ks < 2; ++ks)
                ah[mi][ks] = *(const short8*)(A0 + (wm*128 + 64 + mi*16 + l16)*128
                                              + (((ks*4 + quad) ^ sw) * 16));
        __builtin_amdgcn_s_barrier();
        asm volatile("s_waitcnt lgkmcnt(0)" ::: "memory");
        __builtin_amdgcn_s_setprio(1);
#pragma unroll
        for (int mi = 0; mi < 4; ++mi)
#pragma unroll
            for (int ni = 0; ni < 2; ++ni)
#pragma unroll
                for (int ks = 0; ks < 2; ++ks)
                    acc[4 + mi][ni] = __builtin_amdgcn_mfma_f32_16x16x32_bf16(
                        ah[mi][ks], b0f[ni][ks], acc[4 + mi][ni], 0, 0, 0);
        __builtin_amdgcn_s_setprio(0);
        __builtin_amdgcn_s_barrier();

        // ---- ph3: reads B nh1 frag; stage A-lo(kt0+2); MFMA (mh1,nh1)
#pragma unroll
        for (int ni = 0; ni < 2; ++ni)
#pragma unroll
            for (int ks = 0; ks < 2; ++ks)
                b1f[ni][ks] = *(const short8*)(B0 + (wn*64 + 32 + ni*16 + l16)*128
                                               + (((ks*4 + quad) ^ sw) * 16));
        if (kt0 + 2 < NKT) stA(0, kt0 + 2, 0);
        __builtin_amdgcn_s_barrier();
        asm volatile("s_waitcnt lgkmcnt(0)" ::: "memory");
        __builtin_amdgcn_s_setprio(1);
#pragma unroll
        for (int mi = 0; mi < 4; ++mi)
#pragma unroll
            for (int ni = 0; ni < 2; ++ni)
#pragma unroll
                for (int ks = 0; ks < 2; ++ks)
                    acc[4 + mi][2 + ni] = __builtin_amdgcn_mfma_f32_16x16x32_bf16(
                        ah[mi][ks], b1f[ni][ks], acc[4 + mi][2 + ni], 0, 0, 0);
        __builtin_amdgcn_s_setprio(0);
        __builtin_amdgcn_s_barrier();

        // ---- ph4: stage A-hi(kt0+2)+B-lo(kt0+2); vmcnt(6) -> kt1 complete; MFMA (mh0,nh1)
        if (kt0 + 2 < NKT) {
            stA(0, kt0 + 2, 1);
            stB(0, kt0 + 2, 0);
            asm volatile("s_waitcnt vmcnt(6)" ::: "memory");
        } else {
            asm volatile("s_waitcnt vmcnt(0)" ::: "memory");
        }
        __builtin_amdgcn_s_barrier();
        __builtin_amdgcn_s_setprio(1);
#pragma unroll
        for (int mi = 0; mi < 4; ++mi)
#pragma unroll
            for (int ni = 0; ni < 2; ++ni)
#pragma unroll
                for (int ks = 0; ks < 2; ++ks)
                    acc[mi][2 + ni] = __builtin_amdgcn_mfma_f32_16x16x32_bf16(
                        al[mi][ks], b1f[ni][ks], acc[mi][2 + ni], 0, 0, 0);
        __builtin_amdgcn_s_setprio(0);
        __builtin_amdgcn_s_barrier();

        // ========== K-tile kt1 (buf1) ==========
        // ---- ph5: reads A-lo + B nh0 (buf1); stage B-hi(kt0+2); MFMA (mh0,nh0)
#pragma unroll
        for (int mi = 0; mi < 4; ++mi)
#pragma unroll
            for (int ks = 0; ks < 2; ++ks)
                al[mi][ks] = *(const short8*)(A1 + (wm*128 + mi*16 + l16)*128
                                              + (((ks*4 + quad) ^ sw) * 16));
#pragma unroll
        for (int ni = 0; ni < 2; ++ni)
#pragma unroll
            for (int ks = 0; ks < 2; ++ks)
                b0f[ni][ks] = *(const short8*)(B1 + (wn*64 + ni*16 + l16)*128
                                               + (((ks*4 + quad) ^ sw) * 16));
        if (kt0 + 2 < NKT) stB(0, kt0 + 2, 1);
        __builtin_amdgcn_s_barrier();
        asm volatile("s_waitcnt lgkmcnt(0)" ::: "memory");
        __builtin_amdgcn_s_setprio(1);
#pragma unroll
        for (int mi = 0; mi < 4; ++mi)
#pragma unroll
            for (int ni = 0; ni < 2; ++ni)
#pragma unroll
                for (int ks = 0; ks < 2; ++ks)
                    acc[mi][ni] = __builtin_amdgcn_mfma_f32_16x16x32_bf16(
                        al[mi][ks], b0f[ni][ks], acc[mi][ni], 0, 0, 0);
        __builtin_amdgcn_s_setprio(0);
        __builtin_amdgcn_s_barrier();

        // ---- ph6: reads A-hi (buf1); MFMA (mh1,nh0)
#pragma unroll
        for (int mi = 0; mi < 4; ++mi)
#pragma unroll
            for (int ks = 0; ks < 2; ++ks)
                ah[mi][ks] = *(const short8*)(A1 + (wm*128 + 64 + mi*16 + l16)*128
                                              + (((ks*4 + quad) ^ sw) * 16));
        __builtin_amdgcn_s_barrier();
        asm volatile("s_waitcnt lgkmcnt(0)" ::: "memory");
        __builtin_amdgcn_s_setprio(1);
#pragma unroll
        for (int mi = 0; mi < 4; ++mi)
#pragma unroll
            for (int ni = 0; ni < 2; ++ni)
#pragma unroll
                for (int ks = 0; ks < 2; ++ks)
                    acc[4 + mi][ni] = __builtin_amdgcn_mfma_f32_16x16x32_bf16(
                        ah[mi][ks], b0f[ni][ks], acc[4 + mi][ni], 0, 0, 0);
        __builtin_amdgcn_s_setprio(0);
        __builtin_amdgcn_s_barrier();

        // ---- ph7: reads B nh1 (buf1); stage A-lo(kt1+2); MFMA (mh1,nh1)
#pragma unroll
        for (int ni = 0; ni < 2; ++ni)
#pragma unroll
            for (int ks = 0; ks < 2; ++ks)
                b1f[ni][ks] = *(const short8*)(B1 + (wn*64 + 32 + ni*16 + l16)*128
                                               + (((ks*4 + quad) ^ sw) * 16));
        if (kt1 + 2 < NKT) stA(1, kt1 + 2, 0);
        __builtin_amdgcn_s_barrier();
        asm volatile("s_waitcnt lgkmcnt(0)" ::: "memory");
        __builtin_amdgcn_s_setprio(1);
#pragma unroll
        for (int mi = 0; mi < 4; ++mi)
#pragma unroll
            for (int ni = 0; ni < 2; ++ni)
#pragma unroll
                for (int ks = 0; ks < 2; ++ks)
                    acc[4 + mi][2 + ni] = __builtin_amdgcn_mfma_f32_16x16x32_bf16(
                        ah[mi][ks], b1f[ni][ks], acc[4 + mi][2 + ni], 0, 0, 0);
        __builtin_amdgcn_s_setprio(0);
        __builtin_amdgcn_s_barrier();

        // ---- ph8: stage A-hi+B-lo+B-hi(kt1+2); vmcnt(8) -> kt0+2 complete; MFMA (mh0,nh1)
        if (kt1 + 2 < NKT) {
            stA(1, kt1 + 2, 1);
            stB(1, kt1 + 2, 0);
            stB(1, kt1 + 2, 1);
            asm volatile("s_waitcnt vmcnt(8)" ::: "memory");
        }
        __builtin_amdgcn_s_barrier();
        __builtin_amdgcn_s_setprio(1);
#pragma unroll
        for (int mi = 0; mi < 4; ++mi)
#pragma unroll
            for (int ni = 0; ni < 2; ++ni)
#pragma unroll
                for (int ks = 0; ks < 2; ++ks)
                    acc[mi][2 + ni] = __builtin_amdgcn_mfma_f32_16x16x32_bf16(
                        al[mi][ks], b1f[ni][ks], acc[mi][2 + ni], 0, 0, 0);
        __builtin_amdgcn_s_setprio(0);
        __builtin_amdgcn_s_barrier();
    }

    // ---------- epilogue (same math/layout as verified 128^2 kernel) ----------
#pragma unroll
    for (int mh = 0; mh < 2; ++mh)
#pragma unroll
     for (int mi = 0; mi < 4; ++mi)
#pragma unroll
      for (int nh = 0; nh < 2; ++nh)
#pragma unroll
       for (int ni = 0; ni < 2; ++ni) {
            const int col = bn0 + wn*64 + nh*32 + ni*16 + l16;
            const float bvv = bias[col];
#pragma unroll
            for (int r = 0; r < 4; ++r) {
                const int row = bm0 + wm*128 + mh*64 + mi*16 + quad*4 + r;
                const float v = (acc[mh*4 + mi][nh*2 + ni][r] + bvv) * scale;
                const int bb = row >> 11, t = row & 2047;
                const int hh = col >> 6,  d = col & 63;
                if (sel != 2)
                    out[((size_t)(bb*HEADS + hh)*CTX + t)*HD + d] = f2bf(v);
                else
                    out[((size_t)(bb*HEADS + hh)*HD + d)*CTX + t] = f2bf(v);
            }
       }
}

// ================= projection GEMM (fp32 out), BK=64 =================
__global__ __launch_bounds__(256)
void gemm_proj(const u16* __restrict__ A, const u16* __restrict__ Bw,
               const float* __restrict__ bias, float* __restrict__ out)
{
    __shared__ u16 As[128*64];
    __shared__ u16 Bs[128*64];
    const int tid  = threadIdx.x;
    const int lane = tid & 63;
    const int wid  = tid >> 6;
    const int wm = wid >> 1, wn = wid & 1;
    const int quad = lane >> 4;
    const int l16  = lane & 15;
    const int bm0 = blockIdx.x * 128;
    const int bn0 = blockIdx.y * 128;

    floatx4 acc[4][4] = {};

    const int r0   = tid >> 3;
    const int joff = ((tid & 7) ^ ((tid >> 3) & 7)) * 8;
    const u16* Ag0 = A  + (size_t)(bm0 + r0      ) * EMBED + joff;
    const u16* Ag1 = A  + (size_t)(bm0 + r0 + 32 ) * EMBED + joff;
    const u16* Ag2 = A  + (size_t)(bm0 + r0 + 64 ) * EMBED + joff;
    const u16* Ag3 = A  + (size_t)(bm0 + r0 + 96 ) * EMBED + joff;
    const u16* Bg0 = Bw + (size_t)(bn0 + r0      ) * EMBED + joff;
    const u16* Bg1 = Bw + (size_t)(bn0 + r0 + 32 ) * EMBED + joff;
    const u16* Bg2 = Bw + (size_t)(bn0 + r0 + 64 ) * EMBED + joff;
    const u16* Bg3 = Bw + (size_t)(bn0 + r0 + 96 ) * EMBED + joff;
    char* AsB = (char*)As;
    char* BsB = (char*)Bs;
    const int wbyte = wid * 1024;
    const int fpos0 = (quad ^ (l16 & 7)) * 8;
    const int fpos1 = fpos0 ^ 32;

    for (int kk = 0; kk < EMBED; kk += 64) {
        __syncthreads();
        async16(Ag0 + kk, AsB + wbyte);
        async16(Ag1 + kk, AsB + wbyte + 4096);
        async16(Ag2 + kk, AsB + wbyte + 8192);
        async16(Ag3 + kk, AsB + wbyte + 12288);
        async16(Bg0 + kk, BsB + wbyte);
        async16(Bg1 + kk, BsB + wbyte + 4096);
        async16(Bg2 + kk, BsB + wbyte + 8192);
        async16(Bg3 + kk, BsB + wbyte + 12288);
        __syncthreads();

#pragma unroll
        for (int ks = 0; ks < 2; ks++) {
            const int fp = ks ? fpos1 : fpos0;
            short8 a[4], b[4];
#pragma unroll
            for (int i = 0; i < 4; i++)
                a[i] = *(const short8*)(As + (wm*64 + i*16 + l16)*64 + fp);
#pragma unroll
            for (int i = 0; i < 4; i++)
                b[i] = *(const short8*)(Bs + (wn*64 + i*16 + l16)*64 + fp);
#pragma unroll
            for (int i = 0; i < 4; i++)
#pragma unroll
                for (int j = 0; j < 4; j++)
                    acc[i][j] = __builtin_amdgcn_mfma_f32_16x16x32_bf16(a[i], b[j], acc[i][j], 0, 0, 0);
        }
    }

#pragma unroll
    for (int i = 0; i < 4; i++) {
#pragma unroll
        for (int j = 0; j < 4; j++) {
            const int col = bn0 + wn*64 + j*16 + l16;
            const float bvv = bias[col];
#pragma unroll
            for (int r = 0; r < 4; r++) {
                const int row = bm0 + wm*64 + i*16 + quad*4 + r;
                out[(size_t)row * EMBED + col] = acc[i][j][r] + bvv;
            }
        }
    }
}

// ---------------- flash attention v3: 128 q/block, S^T order, swizzled P ----------------
__global__ __launch_bounds__(256)
void attn_kernel(const u16* __restrict__ Q, const u16* __restrict__ K,
                 const u16* __restrict__ Vt, u16* __restrict__ O)
{
    __shared__ u16 Ks[2][64*64];     // 2 x 8 KB
    __shared__ u16 Vs[2][64*64];     // 2 x 8 KB   Vs[d][ki]
    __shared__ u16 Ps[4*32*64];      // 16 KB, per-wave 32 rows x 64 ki

    const int tid  = threadIdx.x, lane = tid & 63, w = tid >> 6;
    const int quad = lane >> 4, l16 = lane & 15;

    const int lid  = blockIdx.x;            // 0..511
    const int xcd  = lid & 7;
    const int slot = lid >> 3;              // 0..63
    const int bh   = xcd * 8 + (slot >> 3);
    const int bx   = slot & 7;              // 0..7
    const int h    = bh & (HEADS - 1);
    const int b    = bh >> 4;

    const u16* Qh = Q  + (size_t)bh * CTX * HD;
    const u16* Kh = K  + (size_t)bh * CTX * HD;
    const u16* Vh = Vt + (size_t)bh * HD * CTX;

    const int srow = tid >> 3;
    const int joff = ((tid & 7) ^ (srow & 7)) * 8;
    const int wbyte = w * 1024;
    char* PwB = (char*)(Ps + w * 32 * 64);
    const int sw = l16 & 7;                 // swizzle key (row&7 for all our rows)

    auto stage = [&](int kt, int buf) {
        char* kb = (char*)(&Ks[buf][0]) + wbyte;
        char* vb = (char*)(&Vs[buf][0]) + wbyte;
        async16(Kh + (size_t)(kt*64 + srow     )*HD + joff, kb);
        async16(Kh + (size_t)(kt*64 + srow + 32)*HD + joff, kb + 4096);
        async16(Vh + (size_t)(srow     )*CTX + kt*64 + joff, vb);
        async16(Vh + (size_t)(srow + 32)*CTX + kt*64 + joff, vb + 4096);
    };

    int par = 0;
    stage(0, 0);

#pragma unroll 1
    for (int pass = 0; pass < 2; pass++) {
        const int qb  = (pass == 0) ? bx : (15 - bx);
        const int qb0 = qb * 128;
        const int KT  = 2*qb + 2;

        // Q fragments (B-operand: n=q=l16, k=d): qf[subtile][kstep]
        short8 qf[2][2];
#pragma unroll
        for (int st = 0; st < 2; st++)
#pragma unroll
            for (int ks = 0; ks < 2; ks++)
                qf[st][ks] = *(const short8*)(Qh + (size_t)(qb0 + w*32 + st*16 + l16)*HD
                                              + ks*32 + quad*8);

        float lsum[2] = {0.f, 0.f};
        floatx4 o_acc[2][4] = {};

        for (int kt = 0; kt < KT; kt++) {
            __syncthreads();   // drains stage(kt), in flight since previous compute

            if (kt + 1 < KT)      stage(kt + 1, par ^ 1);
            else if (pass == 0)   stage(0,      par ^ 1);

            const char* KcB = (const char*)(&Ks[par][0]);
            const char* VcB = (const char*)(&Vs[par][0]);

            // S^T = K Q^T : m=ki (row=quad*4+r), n=q (col=l16)
            floatx4 s[2][4] = {};
#pragma unroll
            for (int ks = 0; ks < 2; ks++) {
#pragma unroll
                for (int ni = 0; ni < 4; ni++) {
                    short8 kf = *(const short8*)(KcB + (ni*16 + l16)*128
                                                 + (((4*ks + quad) ^ sw) * 16));
                    s[0][ni] = __builtin_amdgcn_mfma_f32_16x16x32_bf16(kf, qf[0][ks], s[0][ni], 0, 0, 0);
                    s[1][ni] = __builtin_amdgcn_mfma_f32_16x16x32_bf16(kf, qf[1][ks], s[1][ni], 0, 0, 0);
                }
            }

            // P = exp2(S'), mask on last two tiles, packed b64 stores to swizzled P
            const bool mt = (kt >= 2*qb);
            const int key0 = kt * 64;
#pragma unroll
            for (int st = 0; st < 2; st++) {
                const int qrow = qb0 + w*32 + st*16 + l16;
#pragma unroll
                for (int ni = 0; ni < 4; ni++) {
                    float p[4];
#pragma unroll
                    for (int r = 0; r < 4; r++) {
                        float v = s[st][ni][r];
                        if (mt) {
                            const int key = key0 + ni*16 + quad*4 + r;
                            if (key > qrow) v = -INFINITY;
                        }
                        p[r] = __builtin_amdgcn_exp2f(v);
                        lsum[st] += p[r];
                    }
                    uint2 pk;
                    pk.x = (__float_as_uint(p[0]) >> 16) | (__float_as_uint(p[1]) & 0xFFFF0000u);
                    pk.y = (__float_as_uint(p[2]) >> 16) | (__float_as_uint(p[3]) & 0xFFFF0000u);
                    *(uint2*)(PwB + (st*16 + l16)*128
                              + (((2*ni + (quad >> 1)) ^ sw) * 16) + (quad & 1) * 8) = pk;
                }
            }

            // O += P V : A=P (m=q), B=Vt rows (n=d, k=ki)
#pragma unroll
            for (int ks = 0; ks < 2; ks++) {
                const int pco = ((4*ks + quad) ^ sw) * 16;
                short8 pf0 = *(const short8*)(PwB + (l16     )*128 + pco);
                short8 pf1 = *(const short8*)(PwB + (16 + l16)*128 + pco);
#pragma unroll
                for (int ni = 0; ni < 4; ni++) {
                    short8 vf = *(const short8*)(VcB + (ni*16 + l16)*128 + pco);
                    o_acc[0][ni] = __builtin_amdgcn_mfma_f32_16x16x32_bf16(pf0, vf, o_acc[0][ni], 0, 0, 0);
                    o_acc[1][ni] = __builtin_amdgcn_mfma_f32_16x16x32_bf16(pf1, vf, o_acc[1][ni], 0, 0, 0);
                }
            }

            par ^= 1;
        }

        // l-sum: reduce across the 4 quads (lane l has sum for q=l&15), then
        // redistribute reciprocal to the C-layout lanes (q = quad*4+r).
        float linv[2][4];
#pragma unroll
        for (int st = 0; st < 2; st++) {
            lsum[st] += __shfl_xor(lsum[st], 16);
            lsum[st] += __shfl_xor(lsum[st], 32);
            const float rinv = 1.f / lsum[st];
#pragma unroll
            for (int r = 0; r < 4; r++)
                linv[st][r] = __shfl(rinv, quad*4 + r);
        }

        u16* Ob = O + ((size_t)b * CTX) * EMBED + (size_t)h * HD;
#pragma unroll
        for (int st = 0; st < 2; st++)
#pragma unroll
            for (int ni = 0; ni < 4; ni++)
#pragma unroll
                for (int r = 0; r < 4; r++) {
                    const int qrow = qb0 + w*32 + st*16 + quad*4 + r;
                    Ob[(size_t)qrow * EMBED + ni*16 + l16] = f2bf(o_acc[st][ni][r] * linv[st][r]);
                }
    }
}

// ---------------- launcher ----------------
extern "C" void kernel_launch(void* const* d_in, const int* in_sizes, int n_in,
                              void* d_out, int out_size, void* d_ws, size_t ws_size,
                              hipStream_t stream) {
    const float* x  = (const float*)d_in[0];
    const float* Wq = (const float*)d_in[1];
    const float* bq = (const float*)d_in[2];
    const float* Wk = (const float*)d_in[3];
    const float* bk = (const float*)d_in[4];
    const float* Wv = (const float*)d_in[5];
    const float* bv = (const float*)d_in[6];
    const float* Wp = (const float*)d_in[7];
    const float* bp = (const float*)d_in[8];

    char* ws = (char*)d_ws;
    const size_t XSZ = (size_t)M_TOT * EMBED * 2;   // 16 MB
    const size_t WSZ = (size_t)EMBED * EMBED * 2;   // 2 MB
    u16* xb  = (u16*)ws;                 ws += XSZ;
    u16* wqb = (u16*)ws;                 ws += WSZ;
    u16* wkb = (u16*)ws;                 ws += WSZ;
    u16* wvb = (u16*)ws;                 ws += WSZ;
    u16* wpb = (u16*)ws;                 ws += WSZ;
    u16* qg  = (u16*)ws;                 ws += XSZ;
    u16* kg  = (u16*)ws;                 ws += XSZ;
    u16* vtg = (u16*)ws;                 ws += XSZ;
    u16* og  = xb;   // x-bf16 dead after QKV GEMM; attn output reuses it

    const int nX = M_TOT * EMBED;
    const int nW = EMBED * EMBED;
    cvt_kernel<<<nX/1024, 256, 0, stream>>>(x, xb, nX);
    cvt_w_kernel<<<dim3(nW/1024, 4), 256, 0, stream>>>(Wq, Wk, Wv, Wp, wqb, wkb, wvb, wpb);

    const float qscale = 0.125f * 1.44269504f;  // 1/sqrt(64) * log2(e)
    gemm_qkv<<<dim3(M_TOT/256, 12), 512, 0, stream>>>(xb, wqb, wkb, wvb, bq, bk, bv,
                                                      qg, kg, vtg, qscale);

    attn_kernel<<<dim3(512), 256, 0, stream>>>(qg, kg, vtg, og);

    gemm_proj<<<dim3(M_TOT/128, EMBED/128), 256, 0, stream>>>(og, wpb, bp, (float*)d_out);
}

// Round 3
// 262.858 us; speedup vs baseline: 1.0712x; 1.0649x over previous
//
#include <hip/hip_runtime.h>
#include <hip/hip_bf16.h>
#include <stdint.h>

#define EMBED 1024
#define HEADS 16
#define CTX   2048
#define BATCH 4
#define HD    64
#define M_TOT (BATCH*CTX)   // 8192

typedef unsigned short u16;
typedef __attribute__((ext_vector_type(8))) short short8;   // 8 bf16 (4 VGPRs)
typedef __attribute__((ext_vector_type(4))) float floatx4;  // MFMA C/D

typedef const __attribute__((address_space(1))) unsigned int g_u32;
typedef __attribute__((address_space(3))) unsigned int l_u32;

__device__ __forceinline__ void async16(const void* g, void* l) {
    __builtin_amdgcn_global_load_lds((g_u32*)g, (l_u32*)l, 16, 0, 0);
}

__device__ __forceinline__ u16 f2bf(float f) {          // round-nearest-even
    uint32_t u = __float_as_uint(f);
    uint32_t r = (u + 0x7FFFu + ((u >> 16) & 1u)) >> 16;
    return (u16)r;
}

// ---------------- fused fp32 -> bf16 convert (x + 4 weight matrices, 1 launch) ----------------
__global__ void cvt_all(const float* __restrict__ x,
                        const float* __restrict__ Wq, const float* __restrict__ Wk,
                        const float* __restrict__ Wv, const float* __restrict__ Wp,
                        u16* __restrict__ xb,
                        u16* __restrict__ wqb, u16* __restrict__ wkb,
                        u16* __restrict__ wvb, u16* __restrict__ wpb) {
    const int b = blockIdx.x;
    const float* src; u16* dst; int base;
    if (b < 8192)       { src = x;  dst = xb;  base = b; }
    else if (b < 9216)  { src = Wq; dst = wqb; base = b - 8192; }
    else if (b < 10240) { src = Wk; dst = wkb; base = b - 9216; }
    else if (b < 11264) { src = Wv; dst = wvb; base = b - 10240; }
    else                { src = Wp; dst = wpb; base = b - 11264; }
    const int i = (base * 256 + threadIdx.x) * 4;
    float4 f = *(const float4*)(src + i);
    ushort4 o;
    o.x = f2bf(f.x); o.y = f2bf(f.y); o.z = f2bf(f.z); o.w = f2bf(f.w);
    *(ushort4*)(dst + i) = o;
}

// ================= fused QKV GEMM, 128x128 tile, BK=64 (R0-verified structure) =================
__global__ __launch_bounds__(256)
void gemm_qkv(const u16* __restrict__ A,
              const u16* __restrict__ Wq, const u16* __restrict__ Wk, const u16* __restrict__ Wv,
              const float* __restrict__ bq, const float* __restrict__ bk, const float* __restrict__ bv,
              u16* __restrict__ oq, u16* __restrict__ ok, u16* __restrict__ ov,
              float qscale)
{
    __shared__ u16 As[128*64];   // 16 KB
    __shared__ u16 Bs[128*64];   // 16 KB
    const int tid  = threadIdx.x;
    const int lane = tid & 63;
    const int wid  = tid >> 6;
    const int wm = wid >> 1, wn = wid & 1;
    const int quad = lane >> 4;
    const int l16  = lane & 15;
    const int bm0 = blockIdx.x * 128;
    const int sel = blockIdx.y >> 3;          // 0=Q 1=K 2=V
    const int bn0 = (blockIdx.y & 7) * 128;

    const u16*  Bw   = (sel == 0) ? Wq : (sel == 1) ? Wk : Wv;
    const float* bias = (sel == 0) ? bq : (sel == 1) ? bk : bv;
    u16*        out  = (sel == 0) ? oq : (sel == 1) ? ok : ov;
    const float scale = (sel == 0) ? qscale : 1.0f;

    floatx4 acc[4][4] = {};

    const int r0   = tid >> 3;
    const int joff = ((tid & 7) ^ ((tid >> 3) & 7)) * 8;   // shorts
    const u16* Ag0 = A  + (size_t)(bm0 + r0      ) * EMBED + joff;
    const u16* Ag1 = A  + (size_t)(bm0 + r0 + 32 ) * EMBED + joff;
    const u16* Ag2 = A  + (size_t)(bm0 + r0 + 64 ) * EMBED + joff;
    const u16* Ag3 = A  + (size_t)(bm0 + r0 + 96 ) * EMBED + joff;
    const u16* Bg0 = Bw + (size_t)(bn0 + r0      ) * EMBED + joff;
    const u16* Bg1 = Bw + (size_t)(bn0 + r0 + 32 ) * EMBED + joff;
    const u16* Bg2 = Bw + (size_t)(bn0 + r0 + 64 ) * EMBED + joff;
    const u16* Bg3 = Bw + (size_t)(bn0 + r0 + 96 ) * EMBED + joff;
    char* AsB = (char*)As;
    char* BsB = (char*)Bs;
    const int wbyte = wid * 1024;

    const int fpos0 = (quad ^ (l16 & 7)) * 8;
    const int fpos1 = fpos0 ^ 32;

    for (int kk = 0; kk < EMBED; kk += 64) {
        __syncthreads();
        async16(Ag0 + kk, AsB + wbyte);
        async16(Ag1 + kk, AsB + wbyte + 4096);
        async16(Ag2 + kk, AsB + wbyte + 8192);
        async16(Ag3 + kk, AsB + wbyte + 12288);
        async16(Bg0 + kk, BsB + wbyte);
        async16(Bg1 + kk, BsB + wbyte + 4096);
        async16(Bg2 + kk, BsB + wbyte + 8192);
        async16(Bg3 + kk, BsB + wbyte + 12288);
        __syncthreads();

#pragma unroll
        for (int ks = 0; ks < 2; ks++) {
            const int fp = ks ? fpos1 : fpos0;
            short8 a[4], b[4];
#pragma unroll
            for (int i = 0; i < 4; i++)
                a[i] = *(const short8*)(As + (wm*64 + i*16 + l16)*64 + fp);
#pragma unroll
            for (int i = 0; i < 4; i++)
                b[i] = *(const short8*)(Bs + (wn*64 + i*16 + l16)*64 + fp);
#pragma unroll
            for (int i = 0; i < 4; i++)
#pragma unroll
                for (int j = 0; j < 4; j++)
                    acc[i][j] = __builtin_amdgcn_mfma_f32_16x16x32_bf16(a[i], b[j], acc[i][j], 0, 0, 0);
        }
    }

#pragma unroll
    for (int i = 0; i < 4; i++) {
#pragma unroll
        for (int j = 0; j < 4; j++) {
            const int col = bn0 + wn*64 + j*16 + l16;
            const float bvv = bias[col];
#pragma unroll
            for (int r = 0; r < 4; r++) {
                const int row = bm0 + wm*64 + i*16 + quad*4 + r;
                const float v = (acc[i][j][r] + bvv) * scale;
                const int bb = row >> 11, t = row & 2047;
                const int hh = col >> 6,  d = col & 63;
                if (sel != 2)
                    out[((size_t)(bb*HEADS + hh)*CTX + t)*HD + d] = f2bf(v);
                else
                    out[((size_t)(bb*HEADS + hh)*HD + d)*CTX + t] = f2bf(v);
            }
        }
    }
}

// ================= projection GEMM (fp32 out), BK=64 =================
__global__ __launch_bounds__(256)
void gemm_proj(const u16* __restrict__ A, const u16* __restrict__ Bw,
               const float* __restrict__ bias, float* __restrict__ out)
{
    __shared__ u16 As[128*64];
    __shared__ u16 Bs[128*64];
    const int tid  = threadIdx.x;
    const int lane = tid & 63;
    const int wid  = tid >> 6;
    const int wm = wid >> 1, wn = wid & 1;
    const int quad = lane >> 4;
    const int l16  = lane & 15;
    const int bm0 = blockIdx.x * 128;
    const int bn0 = blockIdx.y * 128;

    floatx4 acc[4][4] = {};

    const int r0   = tid >> 3;
    const int joff = ((tid & 7) ^ ((tid >> 3) & 7)) * 8;
    const u16* Ag0 = A  + (size_t)(bm0 + r0      ) * EMBED + joff;
    const u16* Ag1 = A  + (size_t)(bm0 + r0 + 32 ) * EMBED + joff;
    const u16* Ag2 = A  + (size_t)(bm0 + r0 + 64 ) * EMBED + joff;
    const u16* Ag3 = A  + (size_t)(bm0 + r0 + 96 ) * EMBED + joff;
    const u16* Bg0 = Bw + (size_t)(bn0 + r0      ) * EMBED + joff;
    const u16* Bg1 = Bw + (size_t)(bn0 + r0 + 32 ) * EMBED + joff;
    const u16* Bg2 = Bw + (size_t)(bn0 + r0 + 64 ) * EMBED + joff;
    const u16* Bg3 = Bw + (size_t)(bn0 + r0 + 96 ) * EMBED + joff;
    char* AsB = (char*)As;
    char* BsB = (char*)Bs;
    const int wbyte = wid * 1024;
    const int fpos0 = (quad ^ (l16 & 7)) * 8;
    const int fpos1 = fpos0 ^ 32;

    for (int kk = 0; kk < EMBED; kk += 64) {
        __syncthreads();
        async16(Ag0 + kk, AsB + wbyte);
        async16(Ag1 + kk, AsB + wbyte + 4096);
        async16(Ag2 + kk, AsB + wbyte + 8192);
        async16(Ag3 + kk, AsB + wbyte + 12288);
        async16(Bg0 + kk, BsB + wbyte);
        async16(Bg1 + kk, BsB + wbyte + 4096);
        async16(Bg2 + kk, BsB + wbyte + 8192);
        async16(Bg3 + kk, BsB + wbyte + 12288);
        __syncthreads();

#pragma unroll
        for (int ks = 0; ks < 2; ks++) {
            const int fp = ks ? fpos1 : fpos0;
            short8 a[4], b[4];
#pragma unroll
            for (int i = 0; i < 4; i++)
                a[i] = *(const short8*)(As + (wm*64 + i*16 + l16)*64 + fp);
#pragma unroll
            for (int i = 0; i < 4; i++)
                b[i] = *(const short8*)(Bs + (wn*64 + i*16 + l16)*64 + fp);
#pragma unroll
            for (int i = 0; i < 4; i++)
#pragma unroll
                for (int j = 0; j < 4; j++)
                    acc[i][j] = __builtin_amdgcn_mfma_f32_16x16x32_bf16(a[i], b[j], acc[i][j], 0, 0, 0);
        }
    }

#pragma unroll
    for (int i = 0; i < 4; i++) {
#pragma unroll
        for (int j = 0; j < 4; j++) {
            const int col = bn0 + wn*64 + j*16 + l16;
            const float bvv = bias[col];
#pragma unroll
            for (int r = 0; r < 4; r++) {
                const int row = bm0 + wm*64 + i*16 + quad*4 + r;
                out[(size_t)row * EMBED + col] = acc[i][j][r] + bvv;
            }
        }
    }
}

// ---------------- flash attention v3: 128 q/block, S^T order, swizzled P ----------------
__global__ __launch_bounds__(256)
void attn_kernel(const u16* __restrict__ Q, const u16* __restrict__ K,
                 const u16* __restrict__ Vt, u16* __restrict__ O)
{
    __shared__ u16 Ks[2][64*64];     // 2 x 8 KB
    __shared__ u16 Vs[2][64*64];     // 2 x 8 KB   Vs[d][ki]
    __shared__ u16 Ps[4*32*64];      // 16 KB, per-wave 32 rows x 64 ki

    const int tid  = threadIdx.x, lane = tid & 63, w = tid >> 6;
    const int quad = lane >> 4, l16 = lane & 15;

    const int lid  = blockIdx.x;            // 0..511
    const int xcd  = lid & 7;
    const int slot = lid >> 3;              // 0..63
    const int bh   = xcd * 8 + (slot >> 3);
    const int bx   = slot & 7;              // 0..7
    const int h    = bh & (HEADS - 1);
    const int b    = bh >> 4;

    const u16* Qh = Q  + (size_t)bh * CTX * HD;
    const u16* Kh = K  + (size_t)bh * CTX * HD;
    const u16* Vh = Vt + (size_t)bh * HD * CTX;

    const int srow = tid >> 3;
    const int joff = ((tid & 7) ^ (srow & 7)) * 8;
    const int wbyte = w * 1024;
    char* PwB = (char*)(Ps + w * 32 * 64);
    const int sw = l16 & 7;                 // swizzle key (row&7 for all our rows)

    auto stage = [&](int kt, int buf) {
        char* kb = (char*)(&Ks[buf][0]) + wbyte;
        char* vb = (char*)(&Vs[buf][0]) + wbyte;
        async16(Kh + (size_t)(kt*64 + srow     )*HD + joff, kb);
        async16(Kh + (size_t)(kt*64 + srow + 32)*HD + joff, kb + 4096);
        async16(Vh + (size_t)(srow     )*CTX + kt*64 + joff, vb);
        async16(Vh + (size_t)(srow + 32)*CTX + kt*64 + joff, vb + 4096);
    };

    int par = 0;
    stage(0, 0);

#pragma unroll 1
    for (int pass = 0; pass < 2; pass++) {
        const int qb  = (pass == 0) ? bx : (15 - bx);
        const int qb0 = qb * 128;
        const int KT  = 2*qb + 2;

        // Q fragments (B-operand: n=q=l16, k=d): qf[subtile][kstep]
        short8 qf[2][2];
#pragma unroll
        for (int st = 0; st < 2; st++)
#pragma unroll
            for (int ks = 0; ks < 2; ks++)
                qf[st][ks] = *(const short8*)(Qh + (size_t)(qb0 + w*32 + st*16 + l16)*HD
                                              + ks*32 + quad*8);

        float lsum[2] = {0.f, 0.f};
        floatx4 o_acc[2][4] = {};

        for (int kt = 0; kt < KT; kt++) {
            __syncthreads();   // drains stage(kt), in flight since previous compute

            if (kt + 1 < KT)      stage(kt + 1, par ^ 1);
            else if (pass == 0)   stage(0,      par ^ 1);

            const char* KcB = (const char*)(&Ks[par][0]);
            const char* VcB = (const char*)(&Vs[par][0]);

            // S^T = K Q^T : m=ki (row=quad*4+r), n=q (col=l16)
            floatx4 s[2][4] = {};
#pragma unroll
            for (int ks = 0; ks < 2; ks++) {
#pragma unroll
                for (int ni = 0; ni < 4; ni++) {
                    short8 kf = *(const short8*)(KcB + (ni*16 + l16)*128
                                                 + (((4*ks + quad) ^ sw) * 16));
                    s[0][ni] = __builtin_amdgcn_mfma_f32_16x16x32_bf16(kf, qf[0][ks], s[0][ni], 0, 0, 0);
                    s[1][ni] = __builtin_amdgcn_mfma_f32_16x16x32_bf16(kf, qf[1][ks], s[1][ni], 0, 0, 0);
                }
            }

            // P = exp2(S'), mask on last two tiles, packed b64 stores to swizzled P
            const bool mt = (kt >= 2*qb);
            const int key0 = kt * 64;
#pragma unroll
            for (int st = 0; st < 2; st++) {
                const int qrow = qb0 + w*32 + st*16 + l16;
#pragma unroll
                for (int ni = 0; ni < 4; ni++) {
                    float p[4];
#pragma unroll
                    for (int r = 0; r < 4; r++) {
                        float v = s[st][ni][r];
                        if (mt) {
                            const int key = key0 + ni*16 + quad*4 + r;
                            if (key > qrow) v = -INFINITY;
                        }
                        p[r] = __builtin_amdgcn_exp2f(v);
                        lsum[st] += p[r];
                    }
                    uint2 pk;
                    pk.x = (__float_as_uint(p[0]) >> 16) | (__float_as_uint(p[1]) & 0xFFFF0000u);
                    pk.y = (__float_as_uint(p[2]) >> 16) | (__float_as_uint(p[3]) & 0xFFFF0000u);
                    *(uint2*)(PwB + (st*16 + l16)*128
                              + (((2*ni + (quad >> 1)) ^ sw) * 16) + (quad & 1) * 8) = pk;
                }
            }

            // O += P V : A=P (m=q), B=Vt rows (n=d, k=ki)
#pragma unroll
            for (int ks = 0; ks < 2; ks++) {
                const int pco = ((4*ks + quad) ^ sw) * 16;
                short8 pf0 = *(const short8*)(PwB + (l16     )*128 + pco);
                short8 pf1 = *(const short8*)(PwB + (16 + l16)*128 + pco);
#pragma unroll
                for (int ni = 0; ni < 4; ni++) {
                    short8 vf = *(const short8*)(VcB + (ni*16 + l16)*128 + pco);
                    o_acc[0][ni] = __builtin_amdgcn_mfma_f32_16x16x32_bf16(pf0, vf, o_acc[0][ni], 0, 0, 0);
                    o_acc[1][ni] = __builtin_amdgcn_mfma_f32_16x16x32_bf16(pf1, vf, o_acc[1][ni], 0, 0, 0);
                }
            }

            par ^= 1;
        }

        // l-sum: reduce across the 4 quads (lane l has sum for q=l&15), then
        // redistribute reciprocal to the C-layout lanes (q = quad*4+r).
        float linv[2][4];
#pragma unroll
        for (int st = 0; st < 2; st++) {
            lsum[st] += __shfl_xor(lsum[st], 16);
            lsum[st] += __shfl_xor(lsum[st], 32);
            const float rinv = 1.f / lsum[st];
#pragma unroll
            for (int r = 0; r < 4; r++)
                linv[st][r] = __shfl(rinv, quad*4 + r);
        }

        u16* Ob = O + ((size_t)b * CTX) * EMBED + (size_t)h * HD;
#pragma unroll
        for (int st = 0; st < 2; st++)
#pragma unroll
            for (int ni = 0; ni < 4; ni++)
#pragma unroll
                for (int r = 0; r < 4; r++) {
                    const int qrow = qb0 + w*32 + st*16 + quad*4 + r;
                    Ob[(size_t)qrow * EMBED + ni*16 + l16] = f2bf(o_acc[st][ni][r] * linv[st][r]);
                }
    }
}

// ---------------- launcher ----------------
extern "C" void kernel_launch(void* const* d_in, const int* in_sizes, int n_in,
                              void* d_out, int out_size, void* d_ws, size_t ws_size,
                              hipStream_t stream) {
    const float* x  = (const float*)d_in[0];
    const float* Wq = (const float*)d_in[1];
    const float* bq = (const float*)d_in[2];
    const float* Wk = (const float*)d_in[3];
    const float* bk = (const float*)d_in[4];
    const float* Wv = (const float*)d_in[5];
    const float* bv = (const float*)d_in[6];
    const float* Wp = (const float*)d_in[7];
    const float* bp = (const float*)d_in[8];

    char* ws = (char*)d_ws;
    const size_t XSZ = (size_t)M_TOT * EMBED * 2;   // 16 MB
    const size_t WSZ = (size_t)EMBED * EMBED * 2;   // 2 MB
    u16* xb  = (u16*)ws;                 ws += XSZ;
    u16* wqb = (u16*)ws;                 ws += WSZ;
    u16* wkb = (u16*)ws;                 ws += WSZ;
    u16* wvb = (u16*)ws;                 ws += WSZ;
    u16* wpb = (u16*)ws;                 ws += WSZ;
    u16* qg  = (u16*)ws;                 ws += XSZ;
    u16* kg  = (u16*)ws;                 ws += XSZ;
    u16* vtg = (u16*)ws;                 ws += XSZ;
    u16* og  = xb;   // x-bf16 dead after QKV GEMM; attn output reuses it

    cvt_all<<<12288, 256, 0, stream>>>(x, Wq, Wk, Wv, Wp, xb, wqb, wkb, wvb, wpb);

    const float qscale = 0.125f * 1.44269504f;  // 1/sqrt(64) * log2(e)
    gemm_qkv<<<dim3(M_TOT/128, 24), 256, 0, stream>>>(xb, wqb, wkb, wvb, bq, bk, bv,
                                                      qg, kg, vtg, qscale);

    attn_kernel<<<dim3(512), 256, 0, stream>>>(qg, kg, vtg, og);

    gemm_proj<<<dim3(M_TOT/128, EMBED/128), 256, 0, stream>>>(og, wpb, bp, (float*)d_out);
}